// Round 1
// baseline (2847.972 us; speedup 1.0000x reference)
//
#include <hip/hip_runtime.h>
#include <math.h>

typedef unsigned short u16;
typedef unsigned int u32;
typedef __attribute__((ext_vector_type(8))) short bf16x8_t;
typedef __attribute__((ext_vector_type(4))) float f32x4_t;

constexpr int SEQ = 1024;
constexpr int EMB = 768;
constexpr int PDIM = 128;
constexpr int NH = 16;
constexpr int HDIM = 48;
constexpr int DMLP = 3072;
constexpr int NFREQ = 256;

__device__ __forceinline__ float bf2f(u16 h) {
  union { u32 u; float f; } v; v.u = ((u32)h) << 16; return v.f;
}
__device__ __forceinline__ u16 f2bf(float f) {
  union { float f; u32 u; } v; v.f = f;
  u32 r = v.u + 0x7fffu + ((v.u >> 16) & 1u);
  return (u16)(r >> 16);
}
__device__ __forceinline__ float silu_f(float x) { return x / (1.f + expf(-x)); }
__device__ __forceinline__ float gelu_t(float x) {
  float x3 = x * x * x;
  return 0.5f * x * (1.f + tanhf(0.7978845608028654f * (x + 0.044715f * x3)));
}

// ---------------- time embedding ----------------
// c1[e] = silu(dot(emb, t0_w[e,:]) + t0_b[e]); one wave per output.
__global__ __launch_bounds__(256) void time1_kernel(
    const float* __restrict__ t, const float* __restrict__ t0_w,
    const float* __restrict__ t0_b, float* __restrict__ c1) {
  int e = (blockIdx.x * 256 + threadIdx.x) >> 6;
  int lane = threadIdx.x & 63;
  float tv = t[0];
  float acc = 0.f;
#pragma unroll
  for (int j = 0; j < 4; j++) {
    int i = lane + j * 64;
    int ii = (i < 128) ? i : (i - 128);
    float fr = expf(-9.210340371976184f * (float)ii / 128.f);
    float a = tv * fr;
    float ev = (i < 128) ? cosf(a) : sinf(a);
    acc += ev * t0_w[(long)e * NFREQ + i];
  }
#pragma unroll
  for (int m = 1; m < 64; m <<= 1) acc += __shfl_xor(acc, m, 64);
  if (lane == 0) {
    float s = acc + t0_b[e];
    c1[e] = silu_f(s);
  }
}

// cs[e] = silu(dot(c1, t2_w[e,:]) + t2_b[e])
__global__ __launch_bounds__(256) void time2_kernel(
    const float* __restrict__ c1, const float* __restrict__ t2_w,
    const float* __restrict__ t2_b, float* __restrict__ cs) {
  int e = (blockIdx.x * 256 + threadIdx.x) >> 6;
  int lane = threadIdx.x & 63;
  float acc = 0.f;
#pragma unroll
  for (int j = 0; j < 12; j++)
    acc += c1[lane + j * 64] * t2_w[(long)e * EMB + lane + j * 64];
#pragma unroll
  for (int m = 1; m < 64; m <<= 1) acc += __shfl_xor(acc, m, 64);
  if (lane == 0) {
    float s = acc + t2_b[e];
    cs[e] = silu_f(s);
  }
}

// ---------------- ada vectors: 8*4608 block rows + 1536 final rows ----------------
__global__ __launch_bounds__(256) void ada_kernel(
    const float* __restrict__ cs,
    const float* __restrict__ blk_w, const float* __restrict__ blk_b,
    const float* __restrict__ fin_w, const float* __restrict__ fin_b,
    float* __restrict__ adas) {
  int r = (blockIdx.x * 256 + threadIdx.x) >> 6;
  int lane = threadIdx.x & 63;
  const float* wr = (r < 36864) ? (blk_w + (long)r * EMB)
                                : (fin_w + (long)(r - 36864) * EMB);
  float acc = 0.f;
#pragma unroll
  for (int j = 0; j < 12; j++)
    acc += cs[lane + j * 64] * wr[lane + j * 64];
#pragma unroll
  for (int m = 1; m < 64; m <<= 1) acc += __shfl_xor(acc, m, 64);
  if (lane == 0) {
    float b = (r < 36864) ? blk_b[r] : fin_b[r - 36864];
    adas[r] = acc + b;
  }
}

// ---------------- bias -> bh (LN over P=128 then 16-head projection) ----------------
// bh[h,l,m] = r*(dot(b, g*w[h]) - mu*S[h]) + T[h]; lane=(head, subpair); K fully in-lane.
__global__ __launch_bounds__(256) void bias_bh_kernel(
    const float* __restrict__ bias, const float* __restrict__ gam,
    const float* __restrict__ bet, const float* __restrict__ w,
    u16* __restrict__ bh) {
  int lane = threadIdx.x & 63;
  int h = lane & 15, sp = lane >> 4;
  float wp[PDIM];
  float S = 0.f, T = 0.f;
#pragma unroll
  for (int j = 0; j < PDIM / 4; j++) {
    float4 wv = *(const float4*)(w + h * PDIM + j * 4);
    float4 gv = *(const float4*)(gam + j * 4);
    float4 bv = *(const float4*)(bet + j * 4);
    wp[j * 4 + 0] = wv.x * gv.x;
    wp[j * 4 + 1] = wv.y * gv.y;
    wp[j * 4 + 2] = wv.z * gv.z;
    wp[j * 4 + 3] = wv.w * gv.w;
    S += wp[j * 4 + 0] + wp[j * 4 + 1] + wp[j * 4 + 2] + wp[j * 4 + 3];
    T += bv.x * wv.x + bv.y * wv.y + bv.z * wv.z + bv.w * wv.w;
  }
  const long ntile = (long)SEQ * SEQ / 4;
  long nw = (long)gridDim.x * 4;
  long wgid = ((long)blockIdx.x * 256 + threadIdx.x) >> 6;
  for (long tile = wgid; tile < ntile; tile += nw) {
    long pair = tile * 4 + sp;
    const float* bp = bias + pair * (long)PDIM;
    float acc = 0.f, s = 0.f, ss = 0.f;
#pragma unroll
    for (int j = 0; j < PDIM / 4; j++) {
      float4 b4 = *(const float4*)(bp + j * 4);
      s += b4.x + b4.y + b4.z + b4.w;
      ss += b4.x * b4.x + b4.y * b4.y + b4.z * b4.z + b4.w * b4.w;
      acc += b4.x * wp[j * 4 + 0] + b4.y * wp[j * 4 + 1] +
             b4.z * wp[j * 4 + 2] + b4.w * wp[j * 4 + 3];
    }
    float mu = s * (1.f / PDIM);
    float r = rsqrtf(ss * (1.f / PDIM) - mu * mu + 1e-6f);
    bh[(long)h * SEQ * SEQ + pair] = f2bf(r * (acc - mu * S) + T);
  }
}

// ---------------- fp32 -> bf16 weight conversion (4 segments) ----------------
__global__ __launch_bounds__(256) void cvt4_kernel(
    const float* __restrict__ s0, int n0, const float* __restrict__ s1, int n1,
    const float* __restrict__ s2, int n2, const float* __restrict__ s3, int n3,
    u16* __restrict__ dst) {
  long total = ((long)n0 + n1 + n2 + n3) >> 2;
  for (long i = (long)blockIdx.x * 256 + threadIdx.x; i < total;
       i += (long)gridDim.x * 256) {
    long e = i << 2;
    const float* s; long off;
    if (e < n0) { s = s0; off = e; }
    else if (e < (long)n0 + n1) { s = s1; off = e - n0; }
    else if (e < (long)n0 + n1 + n2) { s = s2; off = e - n0 - n1; }
    else { s = s3; off = e - n0 - n1 - n2; }
    float4 v = *(const float4*)(s + off);
    ushort4 o;
    o.x = f2bf(v.x); o.y = f2bf(v.y); o.z = f2bf(v.z); o.w = f2bf(v.w);
    *(ushort4*)(dst + e) = o;
  }
}

// ---------------- LN + adaLN modulation -> bf16 ----------------
__global__ __launch_bounds__(256) void ln_mod_kernel(
    const float* __restrict__ x, const float* __restrict__ sh,
    const float* __restrict__ sc, u16* __restrict__ out) {
  int row = blockIdx.x * 4 + (threadIdx.x >> 6);
  int lane = threadIdx.x & 63;
  const float* xr = x + (long)row * EMB;
  float4 xv[3];
  float s = 0.f, ss = 0.f;
#pragma unroll
  for (int j = 0; j < 3; j++) {
    xv[j] = *(const float4*)(xr + j * 256 + lane * 4);
    s += xv[j].x + xv[j].y + xv[j].z + xv[j].w;
    ss += xv[j].x * xv[j].x + xv[j].y * xv[j].y + xv[j].z * xv[j].z + xv[j].w * xv[j].w;
  }
#pragma unroll
  for (int m = 1; m < 64; m <<= 1) {
    s += __shfl_xor(s, m, 64);
    ss += __shfl_xor(ss, m, 64);
  }
  float mu = s * (1.f / EMB);
  float r = rsqrtf(ss * (1.f / EMB) - mu * mu + 1e-6f);
#pragma unroll
  for (int j = 0; j < 3; j++) {
    int c = j * 256 + lane * 4;
    float4 shv = *(const float4*)(sh + c);
    float4 scv = *(const float4*)(sc + c);
    ushort4 o;
    o.x = f2bf((xv[j].x - mu) * r * (1.f + scv.x) + shv.x);
    o.y = f2bf((xv[j].y - mu) * r * (1.f + scv.y) + shv.y);
    o.z = f2bf((xv[j].z - mu) * r * (1.f + scv.z) + shv.z);
    o.w = f2bf((xv[j].w - mu) * r * (1.f + scv.w) + shv.w);
    *(ushort4*)(out + (long)row * EMB + c) = o;
  }
}

// ---------------- softmax (in-place, bf16, row length 1024) ----------------
__global__ __launch_bounds__(256) void softmax_kernel(u16* __restrict__ sp) {
  long row = (long)blockIdx.x * 4 + (threadIdx.x >> 6);
  int lane = threadIdx.x & 63;
  u16* p = sp + row * SEQ;
  uint4 u0 = *(uint4*)(p + lane * 8);
  uint4 u1 = *(uint4*)(p + 512 + lane * 8);
  float v[16];
  u32 uu[8] = {u0.x, u0.y, u0.z, u0.w, u1.x, u1.y, u1.z, u1.w};
#pragma unroll
  for (int i = 0; i < 8; i++) {
    v[2 * i] = bf2f((u16)(uu[i] & 0xffffu));
    v[2 * i + 1] = bf2f((u16)(uu[i] >> 16));
  }
  float mx = v[0];
#pragma unroll
  for (int i = 1; i < 16; i++) mx = fmaxf(mx, v[i]);
#pragma unroll
  for (int m = 1; m < 64; m <<= 1) mx = fmaxf(mx, __shfl_xor(mx, m, 64));
  float sum = 0.f;
#pragma unroll
  for (int i = 0; i < 16; i++) {
    v[i] = expf(v[i] - mx);
    sum += v[i];
  }
#pragma unroll
  for (int m = 1; m < 64; m <<= 1) sum += __shfl_xor(sum, m, 64);
  float inv = 1.f / sum;
#pragma unroll
  for (int i = 0; i < 8; i++)
    uu[i] = (u32)f2bf(v[2 * i] * inv) | ((u32)f2bf(v[2 * i + 1] * inv) << 16);
  *(uint4*)(p + lane * 8) = make_uint4(uu[0], uu[1], uu[2], uu[3]);
  *(uint4*)(p + 512 + lane * 8) = make_uint4(uu[4], uu[5], uu[6], uu[7]);
}

// ---------------- generic bf16 MFMA GEMM: C = A(MxK) * Bt(NxK)^T ----------------
enum { M_PLAIN, M_QKV, M_LOGITS, M_PV, M_RESID, M_GELU };

template <int MODE>
__global__ __launch_bounds__(256) void gemm_bt_kernel(
    const u16* __restrict__ A, long sAz, int lda,
    const u16* __restrict__ Bt, long sBz, int ldb,
    int M, int N, int K,
    const float* __restrict__ bias, const float* __restrict__ gate,
    const u16* __restrict__ addb,
    float* __restrict__ outf, int ldo,
    u16* __restrict__ outb, long sObz, int ldob,
    u16* __restrict__ qout, u16* __restrict__ kout, u16* __restrict__ vtout,
    float qscale) {
  __shared__ __align__(16) u16 As[64][40];
  __shared__ __align__(16) u16 Bs[64][40];
  const int tid = threadIdx.x;
  const int lane = tid & 63, wid = tid >> 6;
  const int bm = blockIdx.y * 64, bn = blockIdx.x * 64;
  const int z = blockIdx.z;
  const u16* Ab = A + (long)z * sAz;
  const u16* Bb = Bt + (long)z * sBz;
  const int ar = tid >> 2, ac = (tid & 3) * 8;
  const int wm = (wid >> 1) * 32, wn = (wid & 1) * 32;
  const int fm = lane & 15, fq = lane >> 4;
  f32x4_t acc[2][2] = {};
  for (int k0 = 0; k0 < K; k0 += 32) {
    uint4 av = make_uint4(0, 0, 0, 0);
    if (k0 + ac < K)
      av = *(const uint4*)(Ab + (long)(bm + ar) * lda + (k0 + ac));
    *(uint4*)(&As[ar][ac]) = av;
    uint4 bv = make_uint4(0, 0, 0, 0);
    if ((bn + ar) < N && (k0 + ac) < K)
      bv = *(const uint4*)(Bb + (long)(bn + ar) * ldb + (k0 + ac));
    *(uint4*)(&Bs[ar][ac]) = bv;
    __syncthreads();
    bf16x8_t a0 = *(const bf16x8_t*)(&As[wm + fm][fq * 8]);
    bf16x8_t a1 = *(const bf16x8_t*)(&As[wm + 16 + fm][fq * 8]);
    bf16x8_t b0 = *(const bf16x8_t*)(&Bs[wn + fm][fq * 8]);
    bf16x8_t b1 = *(const bf16x8_t*)(&Bs[wn + 16 + fm][fq * 8]);
    acc[0][0] = __builtin_amdgcn_mfma_f32_16x16x32_bf16(a0, b0, acc[0][0], 0, 0, 0);
    acc[0][1] = __builtin_amdgcn_mfma_f32_16x16x32_bf16(a0, b1, acc[0][1], 0, 0, 0);
    acc[1][0] = __builtin_amdgcn_mfma_f32_16x16x32_bf16(a1, b0, acc[1][0], 0, 0, 0);
    acc[1][1] = __builtin_amdgcn_mfma_f32_16x16x32_bf16(a1, b1, acc[1][1], 0, 0, 0);
    __syncthreads();
  }
#pragma unroll
  for (int mf = 0; mf < 2; mf++)
#pragma unroll
    for (int nf = 0; nf < 2; nf++) {
      int col = bn + wn + nf * 16 + fm;
      if (col >= N) continue;
      int hh = 0, tt = 0, cc = 0;
      if constexpr (MODE == M_QKV) {
        hh = col / (3 * HDIM);
        int rr = col - hh * 3 * HDIM;
        tt = rr / HDIM;
        cc = rr - tt * HDIM;
      }
#pragma unroll
      for (int r = 0; r < 4; r++) {
        int row = bm + wm + mf * 16 + fq * 4 + r;
        float v = acc[mf][nf][r];
        if constexpr (MODE == M_PLAIN) {
          outf[(long)row * ldo + col] = v + bias[col];
        } else if constexpr (MODE == M_QKV) {
          if (tt == 0)
            qout[(long)hh * SEQ * HDIM + (long)row * HDIM + cc] = f2bf(v * qscale);
          else if (tt == 1)
            kout[(long)hh * SEQ * HDIM + (long)row * HDIM + cc] = f2bf(v);
          else
            vtout[(long)hh * HDIM * SEQ + (long)cc * SEQ + row] = f2bf(v);
        } else if constexpr (MODE == M_LOGITS) {
          long idx = (long)z * sObz + (long)row * ldob + col;
          outb[idx] = f2bf(v + bf2f(addb[idx]));
        } else if constexpr (MODE == M_PV) {
          outb[(long)row * ldob + z * HDIM + col] = f2bf(v);
        } else if constexpr (MODE == M_RESID) {
          long idx = (long)row * ldo + col;
          outf[idx] = outf[idx] + gate[col] * (v + bias[col]);
        } else if constexpr (MODE == M_GELU) {
          outb[(long)row * ldob + col] = f2bf(gelu_t(v + bias[col]));
        }
      }
    }
}

// ---------------- host ----------------
extern "C" void kernel_launch(void* const* d_in, const int* in_sizes, int n_in,
                              void* d_out, int out_size, void* d_ws, size_t ws_size,
                              hipStream_t stream) {
  const float* z = (const float*)d_in[0];
  const float* t = (const float*)d_in[1];
  const float* bias = (const float*)d_in[2];
  const float* p2s_ln_g = (const float*)d_in[3];
  const float* p2s_ln_b = (const float*)d_in[4];
  const float* p2s_w = (const float*)d_in[5];
  const float* t0_w = (const float*)d_in[6];
  const float* t0_b = (const float*)d_in[7];
  const float* t2_w = (const float*)d_in[8];
  const float* t2_b = (const float*)d_in[9];
  const float* blk_proj_w = (const float*)d_in[10];
  const float* blk_o_w = (const float*)d_in[11];
  const float* blk_o_b = (const float*)d_in[12];
  const float* blk_ada_w = (const float*)d_in[13];
  const float* blk_ada_b = (const float*)d_in[14];
  const float* blk_fc1_w = (const float*)d_in[15];
  const float* blk_fc1_b = (const float*)d_in[16];
  const float* blk_fc2_w = (const float*)d_in[17];
  const float* blk_fc2_b = (const float*)d_in[18];
  const float* fin_ada_w = (const float*)d_in[19];
  const float* fin_ada_b = (const float*)d_in[20];
  const float* fin_w = (const float*)d_in[21];
  const float* fin_b = (const float*)d_in[22];

  char* base = (char*)d_ws;
  size_t off = 0;
  auto alloc = [&](size_t bytes) {
    void* p = base + off;
    off += (bytes + 255) & ~(size_t)255;
    return p;
  };
  float* x = (float*)alloc((size_t)SEQ * EMB * 4);
  float* c1 = (float*)alloc(EMB * 4);
  float* cs = (float*)alloc(EMB * 4);
  float* adas = (float*)alloc(38400 * 4);
  u16* hbuf = (u16*)alloc((size_t)SEQ * EMB * 2);
  u16* qb = (u16*)alloc((size_t)NH * SEQ * HDIM * 2);
  u16* kb = (u16*)alloc((size_t)NH * SEQ * HDIM * 2);
  u16* vtb = (u16*)alloc((size_t)NH * SEQ * HDIM * 2);
  u16* y2 = (u16*)alloc((size_t)SEQ * EMB * 2);
  u16* mlp = (u16*)alloc((size_t)SEQ * DMLP * 2);
  u16* bh = (u16*)alloc((size_t)NH * SEQ * SEQ * 2);
  u16* SP = (u16*)alloc((size_t)NH * SEQ * SEQ * 2);
  u16* wbuf = (u16*)alloc((size_t)7077888 * 2);
  u16* wfin = (u16*)alloc((size_t)589824 * 2);
  (void)ws_size; (void)in_sizes; (void)n_in; (void)out_size;

  hipMemcpyAsync(x, z, (size_t)SEQ * EMB * 4, hipMemcpyDeviceToDevice, stream);
  time1_kernel<<<192, 256, 0, stream>>>(t, t0_w, t0_b, c1);
  time2_kernel<<<192, 256, 0, stream>>>(c1, t2_w, t2_b, cs);
  ada_kernel<<<9600, 256, 0, stream>>>(cs, blk_ada_w, blk_ada_b, fin_ada_w, fin_ada_b, adas);
  bias_bh_kernel<<<2048, 256, 0, stream>>>(bias, p2s_ln_g, p2s_ln_b, p2s_w, bh);
  cvt4_kernel<<<576, 256, 0, stream>>>(fin_w, 589824, nullptr, 0, nullptr, 0, nullptr, 0, wfin);

  const float qscale = 1.0f / sqrtf((float)HDIM);
  const int owoff = 2304 * 768;
  const int f1off = owoff + 768 * 768;
  const int f2off = f1off + 3072 * 768;

  for (int d = 0; d < 8; d++) {
    const float* pw = blk_proj_w + (long)d * 2304 * 768;
    const float* ow = blk_o_w + (long)d * 768 * 768;
    const float* f1 = blk_fc1_w + (long)d * 3072 * 768;
    const float* f2 = blk_fc2_w + (long)d * 768 * 3072;
    cvt4_kernel<<<6912, 256, 0, stream>>>(pw, 2304 * 768, ow, 768 * 768,
                                          f1, 3072 * 768, f2, 768 * 3072, wbuf);
    const float* ada = adas + d * 4608;
    ln_mod_kernel<<<256, 256, 0, stream>>>(x, ada + 0, ada + 768, hbuf);
    gemm_bt_kernel<M_QKV><<<dim3(36, 16, 1), 256, 0, stream>>>(
        hbuf, 0, EMB, wbuf, 0, EMB, SEQ, 3 * EMB, EMB,
        nullptr, nullptr, nullptr, nullptr, 0, nullptr, 0, 0,
        qb, kb, vtb, qscale);
    gemm_bt_kernel<M_LOGITS><<<dim3(16, 16, 16), 256, 0, stream>>>(
        qb, (long)SEQ * HDIM, HDIM, kb, (long)SEQ * HDIM, HDIM, SEQ, SEQ, HDIM,
        nullptr, nullptr, bh, nullptr, 0, SP, (long)SEQ * SEQ, SEQ,
        nullptr, nullptr, nullptr, 0.f);
    softmax_kernel<<<4096, 256, 0, stream>>>(SP);
    gemm_bt_kernel<M_PV><<<dim3(1, 16, 16), 256, 0, stream>>>(
        SP, (long)SEQ * SEQ, SEQ, vtb, (long)HDIM * SEQ, SEQ, SEQ, HDIM, SEQ,
        nullptr, nullptr, nullptr, nullptr, 0, y2, 0, EMB,
        nullptr, nullptr, nullptr, 0.f);
    gemm_bt_kernel<M_RESID><<<dim3(12, 16, 1), 256, 0, stream>>>(
        y2, 0, EMB, wbuf + owoff, 0, EMB, SEQ, EMB, EMB,
        blk_o_b + d * EMB, ada + 1536, nullptr, x, EMB, nullptr, 0, 0,
        nullptr, nullptr, nullptr, 0.f);
    ln_mod_kernel<<<256, 256, 0, stream>>>(x, ada + 2304, ada + 3072, hbuf);
    gemm_bt_kernel<M_GELU><<<dim3(48, 16, 1), 256, 0, stream>>>(
        hbuf, 0, EMB, wbuf + f1off, 0, EMB, SEQ, DMLP, EMB,
        blk_fc1_b + d * DMLP, nullptr, nullptr, nullptr, 0, mlp, 0, DMLP,
        nullptr, nullptr, nullptr, 0.f);
    gemm_bt_kernel<M_RESID><<<dim3(12, 16, 1), 256, 0, stream>>>(
        mlp, 0, DMLP, wbuf + f2off, 0, DMLP, SEQ, EMB, DMLP,
        blk_fc2_b + d * EMB, ada + 3840, nullptr, x, EMB, nullptr, 0, 0,
        nullptr, nullptr, nullptr, 0.f);
  }
  ln_mod_kernel<<<256, 256, 0, stream>>>(x, adas + 36864, adas + 36864 + 768, hbuf);
  gemm_bt_kernel<M_PLAIN><<<dim3(12, 16, 1), 256, 0, stream>>>(
      hbuf, 0, EMB, wfin, 0, EMB, SEQ, EMB, EMB,
      fin_b, nullptr, nullptr, (float*)d_out, EMB, nullptr, 0, 0,
      nullptr, nullptr, nullptr, 0.f);
}

// Round 2
// 2423.476 us; speedup vs baseline: 1.1752x; 1.1752x over previous
//
#include <hip/hip_runtime.h>
#include <hip/hip_bf16.h>
#include <math.h>

typedef unsigned short u16;
typedef unsigned int u32;
typedef __attribute__((ext_vector_type(8))) short bf16x8_t;
typedef __attribute__((ext_vector_type(4))) float f32x4_t;

constexpr int SEQ = 1024;
constexpr int EMB = 768;
constexpr int PDIM = 128;
constexpr int NH = 16;
constexpr int HDIM = 48;
constexpr int DMLP = 3072;
constexpr int NFREQ = 256;

__device__ __forceinline__ float bf2f(u16 h) {
  union { u32 u; float f; } v; v.u = ((u32)h) << 16; return v.f;
}
__device__ __forceinline__ u16 f2bf(float f) {
  union { float f; u32 u; } v; v.f = f;
  u32 r = v.u + 0x7fffu + ((v.u >> 16) & 1u);
  return (u16)(r >> 16);
}
__device__ __forceinline__ u32 pack_bf2(float lo, float hi) {
  return (u32)f2bf(lo) | ((u32)f2bf(hi) << 16);
}
__device__ __forceinline__ float silu_f(float x) { return x / (1.f + expf(-x)); }
__device__ __forceinline__ float gelu_t(float x) {
  float x3 = x * x * x;
  return 0.5f * x * (1.f + tanhf(0.7978845608028654f * (x + 0.044715f * x3)));
}

// ---------------- time embedding ----------------
__global__ __launch_bounds__(256) void time1_kernel(
    const float* __restrict__ t, const float* __restrict__ t0_w,
    const float* __restrict__ t0_b, float* __restrict__ c1) {
  int e = (blockIdx.x * 256 + threadIdx.x) >> 6;
  int lane = threadIdx.x & 63;
  float tv = t[0];
  float acc = 0.f;
#pragma unroll
  for (int j = 0; j < 4; j++) {
    int i = lane + j * 64;
    int ii = (i < 128) ? i : (i - 128);
    float fr = expf(-9.210340371976184f * (float)ii / 128.f);
    float a = tv * fr;
    float ev = (i < 128) ? cosf(a) : sinf(a);
    acc += ev * t0_w[(long)e * NFREQ + i];
  }
#pragma unroll
  for (int m = 1; m < 64; m <<= 1) acc += __shfl_xor(acc, m, 64);
  if (lane == 0) {
    float s = acc + t0_b[e];
    c1[e] = silu_f(s);
  }
}

__global__ __launch_bounds__(256) void time2_kernel(
    const float* __restrict__ c1, const float* __restrict__ t2_w,
    const float* __restrict__ t2_b, float* __restrict__ cs) {
  int e = (blockIdx.x * 256 + threadIdx.x) >> 6;
  int lane = threadIdx.x & 63;
  float acc = 0.f;
#pragma unroll
  for (int j = 0; j < 12; j++)
    acc += c1[lane + j * 64] * t2_w[(long)e * EMB + lane + j * 64];
#pragma unroll
  for (int m = 1; m < 64; m <<= 1) acc += __shfl_xor(acc, m, 64);
  if (lane == 0) {
    float s = acc + t2_b[e];
    cs[e] = silu_f(s);
  }
}

// ---------------- ada vectors ----------------
__global__ __launch_bounds__(256) void ada_kernel(
    const float* __restrict__ cs,
    const float* __restrict__ blk_w, const float* __restrict__ blk_b,
    const float* __restrict__ fin_w, const float* __restrict__ fin_b,
    float* __restrict__ adas) {
  int r = (blockIdx.x * 256 + threadIdx.x) >> 6;
  int lane = threadIdx.x & 63;
  const float* wr = (r < 36864) ? (blk_w + (long)r * EMB)
                                : (fin_w + (long)(r - 36864) * EMB);
  float acc = 0.f;
#pragma unroll
  for (int j = 0; j < 12; j++)
    acc += cs[lane + j * 64] * wr[lane + j * 64];
#pragma unroll
  for (int m = 1; m < 64; m <<= 1) acc += __shfl_xor(acc, m, 64);
  if (lane == 0) {
    float b = (r < 36864) ? blk_b[r] : fin_b[r - 36864];
    adas[r] = acc + b;
  }
}

// ---------------- bias -> bh via MFMA ----------------
// Per wave: 16 pairs x 16 heads, K=128, 4 x mfma_16x16x32.
// out[h][pair] = r*(dot(b_raw, g.*w[h]) - mu*S[h]) + T[h].
// Lane (m=lane&15, q=lane>>4) owns pair m's elems {t*32+q*8 .. +8} = A-frag layout.
__global__ __launch_bounds__(256) void bias_bh_kernel(
    const float* __restrict__ bias, const float* __restrict__ gam,
    const float* __restrict__ bet, const float* __restrict__ w,
    u16* __restrict__ bh) {
  const int lane = threadIdx.x & 63;
  const int fm = lane & 15;  // pair-in-group (A) / head (B)
  const int fq = lane >> 4;  // quad

  // --- one-time weight prep: B-frags = (g .* w[fm]) in bf16, plus S, T ---
  bf16x8_t bfrag[4];
  float S = 0.f, T = 0.f;
#pragma unroll
  for (int t = 0; t < 4; t++) {
    int k0 = t * 32 + fq * 8;
    float4 w0 = *(const float4*)(w + fm * PDIM + k0);
    float4 w1 = *(const float4*)(w + fm * PDIM + k0 + 4);
    float4 g0 = *(const float4*)(gam + k0);
    float4 g1 = *(const float4*)(gam + k0 + 4);
    float4 e0 = *(const float4*)(bet + k0);
    float4 e1 = *(const float4*)(bet + k0 + 4);
    float wg[8] = {w0.x * g0.x, w0.y * g0.y, w0.z * g0.z, w0.w * g0.w,
                   w1.x * g1.x, w1.y * g1.y, w1.z * g1.z, w1.w * g1.w};
    S += wg[0] + wg[1] + wg[2] + wg[3] + wg[4] + wg[5] + wg[6] + wg[7];
    T += w0.x * e0.x + w0.y * e0.y + w0.z * e0.z + w0.w * e0.w +
         w1.x * e1.x + w1.y * e1.y + w1.z * e1.z + w1.w * e1.w;
    union { bf16x8_t f; u32 u[4]; } bu;
#pragma unroll
    for (int i = 0; i < 4; i++) bu.u[i] = pack_bf2(wg[2 * i], wg[2 * i + 1]);
    bfrag[t] = bu.f;
  }
  S += __shfl_xor(S, 16, 64); S += __shfl_xor(S, 32, 64);
  T += __shfl_xor(T, 16, 64); T += __shfl_xor(T, 32, 64);

  const long ngroup = (long)SEQ * SEQ / 16;
  const long nwave = (long)gridDim.x * 4;
  long gw = ((long)blockIdx.x * 256 + threadIdx.x) >> 6;
  for (long grp = gw; grp < ngroup; grp += nwave) {
    const float* bp = bias + grp * (16 * PDIM) + (long)fm * PDIM;
    float v[32];
#pragma unroll
    for (int t = 0; t < 4; t++) {
      float4 a0 = *(const float4*)(bp + t * 32 + fq * 8);
      float4 a1 = *(const float4*)(bp + t * 32 + fq * 8 + 4);
      v[t * 8 + 0] = a0.x; v[t * 8 + 1] = a0.y; v[t * 8 + 2] = a0.z; v[t * 8 + 3] = a0.w;
      v[t * 8 + 4] = a1.x; v[t * 8 + 5] = a1.y; v[t * 8 + 6] = a1.z; v[t * 8 + 7] = a1.w;
    }
    float s = 0.f, ss = 0.f;
#pragma unroll
    for (int i = 0; i < 32; i++) { s += v[i]; ss += v[i] * v[i]; }
    s += __shfl_xor(s, 16, 64); s += __shfl_xor(s, 32, 64);
    ss += __shfl_xor(ss, 16, 64); ss += __shfl_xor(ss, 32, 64);

    f32x4_t acc = {};
#pragma unroll
    for (int t = 0; t < 4; t++) {
      union { bf16x8_t f; u32 u[4]; } au;
#pragma unroll
      for (int i = 0; i < 4; i++)
        au.u[i] = pack_bf2(v[t * 8 + 2 * i], v[t * 8 + 2 * i + 1]);
      acc = __builtin_amdgcn_mfma_f32_16x16x32_bf16(au.f, bfrag[t], acc, 0, 0, 0);
    }
    // lane holds D[pair = fq*4+r][head = fm]
    long pbase = grp * 16;
#pragma unroll
    for (int r = 0; r < 4; r++) {
      int p = fq * 4 + r;
      float sp = __shfl(s, p, 64);
      float ssp = __shfl(ss, p, 64);
      float mu = sp * (1.f / PDIM);
      float rr = rsqrtf(ssp * (1.f / PDIM) - mu * mu + 1e-6f);
      float out = rr * (acc[r] - mu * S) + T;
      bh[(long)fm * SEQ * SEQ + pbase + p] = f2bf(out);
    }
  }
}

// ---------------- fp32 -> bf16 weight conversion (4 segments) ----------------
__global__ __launch_bounds__(256) void cvt4_kernel(
    const float* __restrict__ s0, int n0, const float* __restrict__ s1, int n1,
    const float* __restrict__ s2, int n2, const float* __restrict__ s3, int n3,
    u16* __restrict__ dst) {
  long total = ((long)n0 + n1 + n2 + n3) >> 2;
  for (long i = (long)blockIdx.x * 256 + threadIdx.x; i < total;
       i += (long)gridDim.x * 256) {
    long e = i << 2;
    const float* s; long off;
    if (e < n0) { s = s0; off = e; }
    else if (e < (long)n0 + n1) { s = s1; off = e - n0; }
    else if (e < (long)n0 + n1 + n2) { s = s2; off = e - n0 - n1; }
    else { s = s3; off = e - n0 - n1 - n2; }
    float4 v = *(const float4*)(s + off);
    ushort4 o;
    o.x = f2bf(v.x); o.y = f2bf(v.y); o.z = f2bf(v.z); o.w = f2bf(v.w);
    *(ushort4*)(dst + e) = o;
  }
}

// ---------------- LN + adaLN modulation -> bf16 ----------------
__global__ __launch_bounds__(256) void ln_mod_kernel(
    const float* __restrict__ x, const float* __restrict__ sh,
    const float* __restrict__ sc, u16* __restrict__ out) {
  int row = blockIdx.x * 4 + (threadIdx.x >> 6);
  int lane = threadIdx.x & 63;
  const float* xr = x + (long)row * EMB;
  float4 xv[3];
  float s = 0.f, ss = 0.f;
#pragma unroll
  for (int j = 0; j < 3; j++) {
    xv[j] = *(const float4*)(xr + j * 256 + lane * 4);
    s += xv[j].x + xv[j].y + xv[j].z + xv[j].w;
    ss += xv[j].x * xv[j].x + xv[j].y * xv[j].y + xv[j].z * xv[j].z + xv[j].w * xv[j].w;
  }
#pragma unroll
  for (int m = 1; m < 64; m <<= 1) {
    s += __shfl_xor(s, m, 64);
    ss += __shfl_xor(ss, m, 64);
  }
  float mu = s * (1.f / EMB);
  float r = rsqrtf(ss * (1.f / EMB) - mu * mu + 1e-6f);
#pragma unroll
  for (int j = 0; j < 3; j++) {
    int c = j * 256 + lane * 4;
    float4 shv = *(const float4*)(sh + c);
    float4 scv = *(const float4*)(sc + c);
    ushort4 o;
    o.x = f2bf((xv[j].x - mu) * r * (1.f + scv.x) + shv.x);
    o.y = f2bf((xv[j].y - mu) * r * (1.f + scv.y) + shv.y);
    o.z = f2bf((xv[j].z - mu) * r * (1.f + scv.z) + shv.z);
    o.w = f2bf((xv[j].w - mu) * r * (1.f + scv.w) + shv.w);
    *(ushort4*)(out + (long)row * EMB + c) = o;
  }
}

// ---------------- softmax (in-place, bf16, row length 1024) ----------------
__global__ __launch_bounds__(256) void softmax_kernel(u16* __restrict__ sp) {
  long row = (long)blockIdx.x * 4 + (threadIdx.x >> 6);
  int lane = threadIdx.x & 63;
  u16* p = sp + row * SEQ;
  uint4 u0 = *(uint4*)(p + lane * 8);
  uint4 u1 = *(uint4*)(p + 512 + lane * 8);
  float v[16];
  u32 uu[8] = {u0.x, u0.y, u0.z, u0.w, u1.x, u1.y, u1.z, u1.w};
#pragma unroll
  for (int i = 0; i < 8; i++) {
    v[2 * i] = bf2f((u16)(uu[i] & 0xffffu));
    v[2 * i + 1] = bf2f((u16)(uu[i] >> 16));
  }
  float mx = v[0];
#pragma unroll
  for (int i = 1; i < 16; i++) mx = fmaxf(mx, v[i]);
#pragma unroll
  for (int m = 1; m < 64; m <<= 1) mx = fmaxf(mx, __shfl_xor(mx, m, 64));
  float sum = 0.f;
#pragma unroll
  for (int i = 0; i < 16; i++) {
    v[i] = expf(v[i] - mx);
    sum += v[i];
  }
#pragma unroll
  for (int m = 1; m < 64; m <<= 1) sum += __shfl_xor(sum, m, 64);
  float inv = 1.f / sum;
#pragma unroll
  for (int i = 0; i < 8; i++)
    uu[i] = (u32)f2bf(v[2 * i] * inv) | ((u32)f2bf(v[2 * i + 1] * inv) << 16);
  *(uint4*)(p + lane * 8) = make_uint4(uu[0], uu[1], uu[2], uu[3]);
  *(uint4*)(p + 512 + lane * 8) = make_uint4(uu[4], uu[5], uu[6], uu[7]);
}

// ---------------- generic bf16 MFMA GEMM: C = A(MxK) * Bt(NxK)^T ----------------
enum { M_PLAIN, M_QKV, M_LOGITS, M_PV, M_RESID, M_GELU };

template <int MODE>
__global__ __launch_bounds__(256) void gemm_bt_kernel(
    const u16* __restrict__ A, long sAz, int lda,
    const u16* __restrict__ Bt, long sBz, int ldb,
    int M, int N, int K,
    const float* __restrict__ bias, const float* __restrict__ gate,
    const u16* __restrict__ addb,
    float* __restrict__ outf, int ldo,
    u16* __restrict__ outb, long sObz, int ldob,
    u16* __restrict__ qout, u16* __restrict__ kout, u16* __restrict__ vtout,
    float qscale) {
  __shared__ __align__(16) u16 As[64][40];
  __shared__ __align__(16) u16 Bs[64][40];
  const int tid = threadIdx.x;
  const int lane = tid & 63, wid = tid >> 6;
  const int bm = blockIdx.y * 64, bn = blockIdx.x * 64;
  const int z = blockIdx.z;
  const u16* Ab = A + (long)z * sAz;
  const u16* Bb = Bt + (long)z * sBz;
  const int ar = tid >> 2, ac = (tid & 3) * 8;
  const int wm = (wid >> 1) * 32, wn = (wid & 1) * 32;
  const int fm = lane & 15, fq = lane >> 4;
  f32x4_t acc[2][2] = {};
  for (int k0 = 0; k0 < K; k0 += 32) {
    uint4 av = make_uint4(0, 0, 0, 0);
    if (k0 + ac < K)
      av = *(const uint4*)(Ab + (long)(bm + ar) * lda + (k0 + ac));
    *(uint4*)(&As[ar][ac]) = av;
    uint4 bv = make_uint4(0, 0, 0, 0);
    if ((bn + ar) < N && (k0 + ac) < K)
      bv = *(const uint4*)(Bb + (long)(bn + ar) * ldb + (k0 + ac));
    *(uint4*)(&Bs[ar][ac]) = bv;
    __syncthreads();
    bf16x8_t a0 = *(const bf16x8_t*)(&As[wm + fm][fq * 8]);
    bf16x8_t a1 = *(const bf16x8_t*)(&As[wm + 16 + fm][fq * 8]);
    bf16x8_t b0 = *(const bf16x8_t*)(&Bs[wn + fm][fq * 8]);
    bf16x8_t b1 = *(const bf16x8_t*)(&Bs[wn + 16 + fm][fq * 8]);
    acc[0][0] = __builtin_amdgcn_mfma_f32_16x16x32_bf16(a0, b0, acc[0][0], 0, 0, 0);
    acc[0][1] = __builtin_amdgcn_mfma_f32_16x16x32_bf16(a0, b1, acc[0][1], 0, 0, 0);
    acc[1][0] = __builtin_amdgcn_mfma_f32_16x16x32_bf16(a1, b0, acc[1][0], 0, 0, 0);
    acc[1][1] = __builtin_amdgcn_mfma_f32_16x16x32_bf16(a1, b1, acc[1][1], 0, 0, 0);
    __syncthreads();
  }
#pragma unroll
  for (int mf = 0; mf < 2; mf++)
#pragma unroll
    for (int nf = 0; nf < 2; nf++) {
      int col = bn + wn + nf * 16 + fm;
      if (col >= N) continue;
      int hh = 0, tt = 0, cc = 0;
      if constexpr (MODE == M_QKV) {
        hh = col / (3 * HDIM);
        int rr = col - hh * 3 * HDIM;
        tt = rr / HDIM;
        cc = rr - tt * HDIM;
      }
#pragma unroll
      for (int r = 0; r < 4; r++) {
        int row = bm + wm + mf * 16 + fq * 4 + r;
        float v = acc[mf][nf][r];
        if constexpr (MODE == M_PLAIN) {
          outf[(long)row * ldo + col] = v + bias[col];
        } else if constexpr (MODE == M_QKV) {
          if (tt == 0)
            qout[(long)hh * SEQ * HDIM + (long)row * HDIM + cc] = f2bf(v * qscale);
          else if (tt == 1)
            kout[(long)hh * SEQ * HDIM + (long)row * HDIM + cc] = f2bf(v);
          else
            vtout[(long)hh * HDIM * SEQ + (long)cc * SEQ + row] = f2bf(v);
        } else if constexpr (MODE == M_LOGITS) {
          long idx = (long)z * sObz + (long)row * ldob + col;
          outb[idx] = f2bf(v + bf2f(addb[idx]));
        } else if constexpr (MODE == M_PV) {
          outb[(long)row * ldob + z * HDIM + col] = f2bf(v);
        } else if constexpr (MODE == M_RESID) {
          long idx = (long)row * ldo + col;
          outf[idx] = outf[idx] + gate[col] * (v + bias[col]);
        } else if constexpr (MODE == M_GELU) {
          outb[(long)row * ldob + col] = f2bf(gelu_t(v + bias[col]));
        }
      }
    }
}

// ---------------- host ----------------
extern "C" void kernel_launch(void* const* d_in, const int* in_sizes, int n_in,
                              void* d_out, int out_size, void* d_ws, size_t ws_size,
                              hipStream_t stream) {
  const float* z = (const float*)d_in[0];
  const float* t = (const float*)d_in[1];
  const float* bias = (const float*)d_in[2];
  const float* p2s_ln_g = (const float*)d_in[3];
  const float* p2s_ln_b = (const float*)d_in[4];
  const float* p2s_w = (const float*)d_in[5];
  const float* t0_w = (const float*)d_in[6];
  const float* t0_b = (const float*)d_in[7];
  const float* t2_w = (const float*)d_in[8];
  const float* t2_b = (const float*)d_in[9];
  const float* blk_proj_w = (const float*)d_in[10];
  const float* blk_o_w = (const float*)d_in[11];
  const float* blk_o_b = (const float*)d_in[12];
  const float* blk_ada_w = (const float*)d_in[13];
  const float* blk_ada_b = (const float*)d_in[14];
  const float* blk_fc1_w = (const float*)d_in[15];
  const float* blk_fc1_b = (const float*)d_in[16];
  const float* blk_fc2_w = (const float*)d_in[17];
  const float* blk_fc2_b = (const float*)d_in[18];
  const float* fin_ada_w = (const float*)d_in[19];
  const float* fin_ada_b = (const float*)d_in[20];
  const float* fin_w = (const float*)d_in[21];
  const float* fin_b = (const float*)d_in[22];

  char* base = (char*)d_ws;
  size_t off = 0;
  auto alloc = [&](size_t bytes) {
    void* p = base + off;
    off += (bytes + 255) & ~(size_t)255;
    return p;
  };
  float* x = (float*)alloc((size_t)SEQ * EMB * 4);
  float* c1 = (float*)alloc(EMB * 4);
  float* cs = (float*)alloc(EMB * 4);
  float* adas = (float*)alloc(38400 * 4);
  u16* hbuf = (u16*)alloc((size_t)SEQ * EMB * 2);
  u16* qb = (u16*)alloc((size_t)NH * SEQ * HDIM * 2);
  u16* kb = (u16*)alloc((size_t)NH * SEQ * HDIM * 2);
  u16* vtb = (u16*)alloc((size_t)NH * SEQ * HDIM * 2);
  u16* y2 = (u16*)alloc((size_t)SEQ * EMB * 2);
  u16* mlp = (u16*)alloc((size_t)SEQ * DMLP * 2);
  u16* bh = (u16*)alloc((size_t)NH * SEQ * SEQ * 2);
  u16* SP = (u16*)alloc((size_t)NH * SEQ * SEQ * 2);
  u16* wbuf = (u16*)alloc((size_t)7077888 * 2);
  u16* wfin = (u16*)alloc((size_t)589824 * 2);
  (void)ws_size; (void)in_sizes; (void)n_in; (void)out_size;

  hipMemcpyAsync(x, z, (size_t)SEQ * EMB * 4, hipMemcpyDeviceToDevice, stream);
  time1_kernel<<<192, 256, 0, stream>>>(t, t0_w, t0_b, c1);
  time2_kernel<<<192, 256, 0, stream>>>(c1, t2_w, t2_b, cs);
  ada_kernel<<<9600, 256, 0, stream>>>(cs, blk_ada_w, blk_ada_b, fin_ada_w, fin_ada_b, adas);
  bias_bh_kernel<<<1024, 256, 0, stream>>>(bias, p2s_ln_g, p2s_ln_b, p2s_w, bh);
  cvt4_kernel<<<576, 256, 0, stream>>>(fin_w, 589824, nullptr, 0, nullptr, 0, nullptr, 0, wfin);

  const float qscale = 1.0f / sqrtf((float)HDIM);
  const int owoff = 2304 * 768;
  const int f1off = owoff + 768 * 768;
  const int f2off = f1off + 3072 * 768;

  for (int d = 0; d < 8; d++) {
    const float* pw = blk_proj_w + (long)d * 2304 * 768;
    const float* ow = blk_o_w + (long)d * 768 * 768;
    const float* f1 = blk_fc1_w + (long)d * 3072 * 768;
    const float* f2 = blk_fc2_w + (long)d * 768 * 3072;
    cvt4_kernel<<<6912, 256, 0, stream>>>(pw, 2304 * 768, ow, 768 * 768,
                                          f1, 3072 * 768, f2, 768 * 3072, wbuf);
    const float* ada = adas + d * 4608;
    ln_mod_kernel<<<256, 256, 0, stream>>>(x, ada + 0, ada + 768, hbuf);
    gemm_bt_kernel<M_QKV><<<dim3(36, 16, 1), 256, 0, stream>>>(
        hbuf, 0, EMB, wbuf, 0, EMB, SEQ, 3 * EMB, EMB,
        nullptr, nullptr, nullptr, nullptr, 0, nullptr, 0, 0,
        qb, kb, vtb, qscale);
    gemm_bt_kernel<M_LOGITS><<<dim3(16, 16, 16), 256, 0, stream>>>(
        qb, (long)SEQ * HDIM, HDIM, kb, (long)SEQ * HDIM, HDIM, SEQ, SEQ, HDIM,
        nullptr, nullptr, bh, nullptr, 0, SP, (long)SEQ * SEQ, SEQ,
        nullptr, nullptr, nullptr, 0.f);
    softmax_kernel<<<4096, 256, 0, stream>>>(SP);
    gemm_bt_kernel<M_PV><<<dim3(1, 16, 16), 256, 0, stream>>>(
        SP, (long)SEQ * SEQ, SEQ, vtb, (long)HDIM * SEQ, SEQ, SEQ, HDIM, SEQ,
        nullptr, nullptr, nullptr, nullptr, 0, y2, 0, EMB,
        nullptr, nullptr, nullptr, 0.f);
    gemm_bt_kernel<M_RESID><<<dim3(12, 16, 1), 256, 0, stream>>>(
        y2, 0, EMB, wbuf + owoff, 0, EMB, SEQ, EMB, EMB,
        blk_o_b + d * EMB, ada + 1536, nullptr, x, EMB, nullptr, 0, 0,
        nullptr, nullptr, nullptr, 0.f);
    ln_mod_kernel<<<256, 256, 0, stream>>>(x, ada + 2304, ada + 3072, hbuf);
    gemm_bt_kernel<M_GELU><<<dim3(48, 16, 1), 256, 0, stream>>>(
        hbuf, 0, EMB, wbuf + f1off, 0, EMB, SEQ, DMLP, EMB,
        blk_fc1_b + d * DMLP, nullptr, nullptr, nullptr, 0, mlp, 0, DMLP,
        nullptr, nullptr, nullptr, 0.f);
    gemm_bt_kernel<M_RESID><<<dim3(12, 16, 1), 256, 0, stream>>>(
        mlp, 0, DMLP, wbuf + f2off, 0, DMLP, SEQ, EMB, DMLP,
        blk_fc2_b + d * EMB, ada + 3840, nullptr, x, EMB, nullptr, 0, 0,
        nullptr, nullptr, nullptr, 0.f);
  }
  ln_mod_kernel<<<256, 256, 0, stream>>>(x, adas + 36864, adas + 36864 + 768, hbuf);
  gemm_bt_kernel<M_PLAIN><<<dim3(12, 16, 1), 256, 0, stream>>>(
      hbuf, 0, EMB, wfin, 0, EMB, SEQ, EMB, EMB,
      fin_b, nullptr, nullptr, (float*)d_out, EMB, nullptr, 0, 0,
      nullptr, nullptr, nullptr, 0.f);
}